// Round 1
// baseline (766.202 us; speedup 1.0000x reference)
//
#include <hip/hip_runtime.h>
#include <hip/hip_fp16.h>

typedef __attribute__((ext_vector_type(4))) float f32x4;
typedef __attribute__((ext_vector_type(8))) short s16x8;
typedef __attribute__((ext_vector_type(4))) short s16x4;
typedef unsigned short u16;

__device__ __forceinline__ u16 f2bf(float f) {
    union { float f; unsigned u; } x; x.f = f;
    return (u16)((x.u + 0x7fffu + ((x.u >> 16) & 1u)) >> 16);
}
__device__ __forceinline__ float bf2f(u16 b) {
    union { unsigned u; float f; } x; x.u = ((unsigned)b) << 16;
    return x.f;
}

__device__ __forceinline__ void ld16(const void* g, void* l) {
    __builtin_amdgcn_global_load_lds(
        (const __attribute__((address_space(1))) unsigned int*)g,
        (__attribute__((address_space(3))) unsigned int*)l, 16, 0, 0);
}

// ---------------------------------------------------------------------------
// Core 128x128 tile GEMM, B^T form: C[m][n] = sum_k A[m][k] * B[n][k].
// A, B row-major with leading dims lda/ldb (elements). 256 threads, 4 waves,
// each wave owns a 64x64 sub-tile (4x4 of 16x16x32 bf16 MFMA).
// LDS staged via global_load_lds width=16 (wave-uniform base + lane*16).
// ---------------------------------------------------------------------------
__device__ __forceinline__ void gemm_core(const u16* A, long lda, const u16* B, long ldb,
                                          int m0, int n0, int kEnd,
                                          f32x4 acc[4][4], u16* sA, u16* sB)
{
    const int t    = threadIdx.x;
    const int lane = t & 63;
    const int wave = t >> 6;
    const int wm   = (wave & 1) << 6;
    const int wn   = (wave >> 1) << 6;
    const int lm   = lane & 15;
    const int lg   = lane >> 4;
    const int sr   = t >> 2;          // staging row 0..63
    const int sc   = (t & 3) << 3;    // staging col (elements), 8-elem chunks
    const u16* gA0 = A + (long)(m0 + sr) * lda + sc;
    const u16* gA1 = A + (long)(m0 + 64 + sr) * lda + sc;
    const u16* gB0 = B + (long)(n0 + sr) * ldb + sc;
    const u16* gB1 = B + (long)(n0 + 64 + sr) * ldb + sc;
    u16* dA0 = sA + t * 8;  u16* dA1 = sA + 2048 + t * 8;
    u16* dB0 = sB + t * 8;  u16* dB1 = sB + 2048 + t * 8;

    for (int k0 = 0; k0 < kEnd; k0 += 32) {
        __syncthreads();                 // protect LDS from previous iter readers
        ld16(gA0 + k0, dA0);
        ld16(gA1 + k0, dA1);
        ld16(gB0 + k0, dB0);
        ld16(gB1 + k0, dB1);
        __syncthreads();                 // drains vmcnt for global_load_lds

        s16x8 af[4], bf[4];
#pragma unroll
        for (int i = 0; i < 4; i++) {
            af[i] = *(const s16x8*)&sA[(wm + i * 16 + lm) * 32 + lg * 8];
            bf[i] = *(const s16x8*)&sB[(wn + i * 16 + lm) * 32 + lg * 8];
        }
#pragma unroll
        for (int i = 0; i < 4; i++)
#pragma unroll
            for (int j = 0; j < 4; j++)
                acc[i][j] = __builtin_amdgcn_mfma_f32_16x16x32_bf16(af[i], bf[j], acc[i][j], 0, 0, 0);
    }
}

// ---------------------------------------------------------------------------
// Conversions
// ---------------------------------------------------------------------------
__global__ void convert_x(const float* __restrict__ X, u16* __restrict__ Xb) {
    long idx = ((long)blockIdx.x * 256 + threadIdx.x) * 4;
    f32x4 v = *(const f32x4*)&X[idx];
    s16x4 o;
    o.x = (short)f2bf(v.x); o.y = (short)f2bf(v.y);
    o.z = (short)f2bf(v.z); o.w = (short)f2bf(v.w);
    *(s16x4*)&Xb[idx] = o;
}

// W[k][n] fp32 -> Wt[n][k] bf16, 64x64 LDS tile transpose. grid (256, 3)
__global__ void convert_w(const float* __restrict__ Wk, const float* __restrict__ Wq,
                          const float* __restrict__ Wv,
                          u16* __restrict__ Wkt, u16* __restrict__ Wqt, u16* __restrict__ Wvt) {
    const float* W; u16* O;
    if (blockIdx.y == 0)      { W = Wk; O = Wkt; }
    else if (blockIdx.y == 1) { W = Wq; O = Wqt; }
    else                      { W = Wv; O = Wvt; }
    __shared__ u16 tile[64][65];
    int k0 = (blockIdx.x >> 4) << 6, n0 = (blockIdx.x & 15) << 6;
    int t = threadIdx.x;
    int rr = t >> 4, cc = (t & 15) << 2;
#pragma unroll
    for (int i = 0; i < 4; i++) {
        int row = rr + i * 16;
        f32x4 v = *(const f32x4*)&W[(long)(k0 + row) * 1024 + n0 + cc];
        tile[row][cc + 0] = f2bf(v.x); tile[row][cc + 1] = f2bf(v.y);
        tile[row][cc + 2] = f2bf(v.z); tile[row][cc + 3] = f2bf(v.w);
    }
    __syncthreads();
#pragma unroll
    for (int i = 0; i < 4; i++) {
        int row = rr + i * 16;   // output row (n-dim)
        s16x4 pk;
        pk.x = (short)tile[cc + 0][row]; pk.y = (short)tile[cc + 1][row];
        pk.z = (short)tile[cc + 2][row]; pk.w = (short)tile[cc + 3][row];
        *(s16x4*)&O[(long)(n0 + row) * 1024 + k0 + cc] = pk;
    }
}

// ---------------------------------------------------------------------------
// Projection GEMMs: C = Xb @ Wt^T.  M=16384, N=1024, K=1024.
// ---------------------------------------------------------------------------
__global__ __launch_bounds__(256, 2) void proj_qk(const u16* __restrict__ X,
                                                  const u16* __restrict__ Wt,
                                                  u16* __restrict__ O) {
    __shared__ u16 sA[4096], sB[4096];
    f32x4 acc[4][4] = {};
    int m0 = (blockIdx.x >> 3) * 128, n0 = (blockIdx.x & 7) * 128;
    gemm_core(X, 1024, Wt, 1024, m0, n0, 1024, acc, sA, sB);
    int lane = threadIdx.x & 63, wave = threadIdx.x >> 6;
    int wm = (wave & 1) << 6, wn = (wave >> 1) << 6, lm = lane & 15, lg = lane >> 4;
#pragma unroll
    for (int i = 0; i < 4; i++)
#pragma unroll
        for (int j = 0; j < 4; j++)
#pragma unroll
            for (int r = 0; r < 4; r++) {
                int row = m0 + wm + i * 16 + lg * 4 + r;
                int col = n0 + wn + j * 16 + lm;
                O[(long)row * 1024 + col] = f2bf(acc[i][j][r]);
            }
}

// V projection, written transposed: Vt[b][a][s] bf16 (per-batch 1024x4096)
__global__ __launch_bounds__(256, 2) void proj_v(const u16* __restrict__ X,
                                                 const u16* __restrict__ Wt,
                                                 u16* __restrict__ O) {
    __shared__ u16 sA[4096], sB[4096];
    f32x4 acc[4][4] = {};
    int m0 = (blockIdx.x >> 3) * 128, n0 = (blockIdx.x & 7) * 128;
    gemm_core(X, 1024, Wt, 1024, m0, n0, 1024, acc, sA, sB);
    int lane = threadIdx.x & 63, wave = threadIdx.x >> 6;
    int wm = (wave & 1) << 6, wn = (wave >> 1) << 6, lm = lane & 15, lg = lane >> 4;
#pragma unroll
    for (int i = 0; i < 4; i++)
#pragma unroll
        for (int j = 0; j < 4; j++) {
            int row0 = m0 + wm + i * 16 + lg * 4;
            int col  = n0 + wn + j * 16 + lm;
            int b = row0 >> 12, s = row0 & 4095;
            s16x4 pk;
            pk.x = (short)f2bf(acc[i][j][0]); pk.y = (short)f2bf(acc[i][j][1]);
            pk.z = (short)f2bf(acc[i][j][2]); pk.w = (short)f2bf(acc[i][j][3]);
            *(s16x4*)&O[(long)b * 4194304 + (long)col * 4096 + s] = pk;
        }
}

// ---------------------------------------------------------------------------
// S = (Q K^T) / 32, causal; only lower-triangular 128x128 tiles (528/batch).
// S stored as f16 (precision for the exp argument). Masked entries: -30000.
// ---------------------------------------------------------------------------
__global__ __launch_bounds__(256, 2) void sgemm_causal(const u16* __restrict__ Q,
                                                       const u16* __restrict__ K,
                                                       u16* __restrict__ S,
                                                       int blocksPerBatch) {
    __shared__ u16 sA[4096], sB[4096];
    int b = blockIdx.x / blocksPerBatch;
    int tt = blockIdx.x % blocksPerBatch;
    int it = (int)((sqrtf(8.0f * tt + 1.0f) - 1.0f) * 0.5f);
    while ((it + 1) * (it + 2) / 2 <= tt) ++it;
    while (it * (it + 1) / 2 > tt) --it;
    int jt = tt - it * (it + 1) / 2;

    const u16* A  = Q + (long)b * 4194304;
    const u16* Bt = K + (long)b * 4194304;
    f32x4 acc[4][4] = {};
    gemm_core(A, 1024, Bt, 1024, it * 128, jt * 128, 1024, acc, sA, sB);

    int lane = threadIdx.x & 63, wave = threadIdx.x >> 6;
    int wm = (wave & 1) << 6, wn = (wave >> 1) << 6, lm = lane & 15, lg = lane >> 4;
#pragma unroll
    for (int i = 0; i < 4; i++)
#pragma unroll
        for (int j = 0; j < 4; j++)
#pragma unroll
            for (int r = 0; r < 4; r++) {
                int gi = it * 128 + wm + i * 16 + lg * 4 + r;
                int gj = jt * 128 + wn + j * 16 + lm;
                float v = acc[i][j][r] * 0.03125f;
                if (gj > gi) v = -30000.0f;
                S[((long)b * 4096 + gi) * 4096 + gj] = __half_as_ushort(__float2half(v));
            }
}

// ---------------------------------------------------------------------------
// Row softmax: reads f16 scores, writes bf16 probs in place, stores 1/l.
// One wave per row; processes cols [0, tile_end) so diagonal-tile entries
// past the causal boundary become exact 0.
// ---------------------------------------------------------------------------
__global__ __launch_bounds__(256) void row_softmax(u16* __restrict__ S,
                                                   float* __restrict__ inv_l,
                                                   int rowBlocksPerBatch) {
    int wave = threadIdx.x >> 6, lane = threadIdx.x & 63;
    int b  = blockIdx.x / rowBlocksPerBatch;
    int rb = blockIdx.x % rowBlocksPerBatch;
    int r  = rb * 4 + wave;
    u16* row = S + ((long)b * 4096 + r) * 4096;
    int end = ((r >> 7) + 1) << 7;

    float m = -1e30f;
    for (int c = lane * 4; c < end; c += 256) {
        s16x4 v = *(const s16x4*)&row[c];
        m = fmaxf(m, __half2float(__ushort_as_half((u16)v.x)));
        m = fmaxf(m, __half2float(__ushort_as_half((u16)v.y)));
        m = fmaxf(m, __half2float(__ushort_as_half((u16)v.z)));
        m = fmaxf(m, __half2float(__ushort_as_half((u16)v.w)));
    }
#pragma unroll
    for (int o = 32; o; o >>= 1) m = fmaxf(m, __shfl_xor(m, o, 64));

    float l = 0.0f;
    const float LOG2E = 1.44269504088896f;
    for (int c = lane * 4; c < end; c += 256) {
        s16x4 v = *(const s16x4*)&row[c];
        float p0 = exp2f((__half2float(__ushort_as_half((u16)v.x)) - m) * LOG2E);
        float p1 = exp2f((__half2float(__ushort_as_half((u16)v.y)) - m) * LOG2E);
        float p2 = exp2f((__half2float(__ushort_as_half((u16)v.z)) - m) * LOG2E);
        float p3 = exp2f((__half2float(__ushort_as_half((u16)v.w)) - m) * LOG2E);
        s16x4 o;
        o.x = (short)f2bf(p0); o.y = (short)f2bf(p1);
        o.z = (short)f2bf(p2); o.w = (short)f2bf(p3);
        *(s16x4*)&row[c] = o;
        l += p0 + p1 + p2 + p3;
    }
#pragma unroll
    for (int o = 32; o; o >>= 1) l += __shfl_xor(l, o, 64);
    if (lane == 0) inv_l[b * 4096 + r] = 1.0f / l;
}

// ---------------------------------------------------------------------------
// O = P @ V (via Vt), scaled by 1/l, fp32 out. K-range limited to j <= i tiles.
// ---------------------------------------------------------------------------
__global__ __launch_bounds__(256, 2) void pv_gemm(const u16* __restrict__ P,
                                                  const u16* __restrict__ Vt,
                                                  const float* __restrict__ inv_l,
                                                  float* __restrict__ Out,
                                                  int blocksPerBatch) {
    __shared__ u16 sA[4096], sB[4096];
    int b = blockIdx.x / blocksPerBatch;
    int q = blockIdx.x % blocksPerBatch;
    int it = 31 - (q >> 3);     // reversed: heaviest tiles dispatch first
    int at = q & 7;

    const u16* A  = P  + (long)b * 16777216;
    const u16* Bt = Vt + (long)b * 4194304;
    f32x4 acc[4][4] = {};
    gemm_core(A, 4096, Bt, 4096, it * 128, at * 128, (it + 1) * 128, acc, sA, sB);

    int lane = threadIdx.x & 63, wave = threadIdx.x >> 6;
    int wm = (wave & 1) << 6, wn = (wave >> 1) << 6, lm = lane & 15, lg = lane >> 4;
#pragma unroll
    for (int i = 0; i < 4; i++)
#pragma unroll
        for (int j = 0; j < 4; j++)
#pragma unroll
            for (int r = 0; r < 4; r++) {
                int gi = it * 128 + wm + i * 16 + lg * 4 + r;
                int ga = at * 128 + wn + j * 16 + lm;
                Out[((long)b * 4096 + gi) * 1024 + ga] = acc[i][j][r] * inv_l[b * 4096 + gi];
            }
}

// ---------------------------------------------------------------------------
extern "C" void kernel_launch(void* const* d_in, const int* in_sizes, int n_in,
                              void* d_out, int out_size, void* d_ws, size_t ws_size,
                              hipStream_t stream) {
    const float* X  = (const float*)d_in[0];
    const float* Wk = (const float*)d_in[1];
    const float* Wq = (const float*)d_in[2];
    const float* Wv = (const float*)d_in[3];
    float* Out = (float*)d_out;

    char* w = (char*)d_ws;
    u16* Xb  = (u16*)(w);                    // 33,554,432 B
    u16* Qb  = (u16*)(w + 33554432);         // 33,554,432 B
    u16* Kb  = (u16*)(w + 67108864);         // 33,554,432 B
    u16* Vt  = (u16*)(w + 100663296);        // 33,554,432 B (bf16, [b][a][s])
    u16* Wkt = (u16*)(w + 134217728);        //  2,097,152 B
    u16* Wqt = (u16*)(w + 136314880);        //  2,097,152 B
    u16* Wvt = (u16*)(w + 138412032);        //  2,097,152 B
    float* invl = (float*)(w + 140509184);   //     65,536 B
    u16* S   = (u16*)(w + 140574720);        // 134,217,728 B (all-batch) or 33,554,432 (per-batch)

    bool allBatch = ws_size >= (size_t)274792448;

    convert_x<<<16384, 256, 0, stream>>>(X, Xb);
    convert_w<<<dim3(256, 3), 256, 0, stream>>>(Wk, Wq, Wv, Wkt, Wqt, Wvt);

    proj_qk<<<1024, 256, 0, stream>>>(Xb, Wqt, Qb);
    proj_qk<<<1024, 256, 0, stream>>>(Xb, Wkt, Kb);
    proj_v <<<1024, 256, 0, stream>>>(Xb, Wvt, Vt);

    if (allBatch) {
        sgemm_causal<<<4 * 528, 256, 0, stream>>>(Qb, Kb, S, 528);
        row_softmax <<<4 * 1024, 256, 0, stream>>>(S, invl, 1024);
        pv_gemm     <<<4 * 256, 256, 0, stream>>>(S, Vt, invl, Out, 256);
    } else {
        for (int b = 0; b < 4; b++) {
            sgemm_causal<<<528, 256, 0, stream>>>(Qb + (long)b * 4194304,
                                                  Kb + (long)b * 4194304, S, 528);
            row_softmax <<<1024, 256, 0, stream>>>(S, invl + b * 4096, 1024);
            pv_gemm     <<<256, 256, 0, stream>>>(S, Vt + (long)b * 4194304,
                                                  invl + b * 4096,
                                                  Out + (long)b * 4194304, 256);
        }
    }
}

// Round 2
// 509.766 us; speedup vs baseline: 1.5030x; 1.5030x over previous
//
#include <hip/hip_runtime.h>
#include <hip/hip_fp16.h>

typedef __attribute__((ext_vector_type(4))) float f32x4;
typedef __attribute__((ext_vector_type(8))) short s16x8;
typedef __attribute__((ext_vector_type(4))) short s16x4;
typedef unsigned short u16;
typedef unsigned int u32;

__device__ __forceinline__ u16 f2bf(float f) {
    union { float f; unsigned u; } x; x.f = f;
    return (u16)((x.u + 0x7fffu + ((x.u >> 16) & 1u)) >> 16);
}

__device__ __forceinline__ void ld16(const void* g, void* l) {
    __builtin_amdgcn_global_load_lds(
        (const __attribute__((address_space(1))) unsigned int*)g,
        (__attribute__((address_space(3))) unsigned int*)l, 16, 0, 0);
}

// ---------------------------------------------------------------------------
// One 32-wide K-step of the 128x128 tile GEMM: stage 4x (64 rows x 32 cols)
// via global_load_lds width=16, then 16 MFMA. LDS layout is XOR-swizzled:
// slot (row*4 + s) holds global chunk s ^ ((row>>1)&3), so ds_read_b128 of a
// fragment hits slot%8 == row%8 for each 16-lane group (2-way = free).
// ---------------------------------------------------------------------------
__device__ __forceinline__ void kstep(const u16* gA0, const u16* gA1,
                                      const u16* gB0, const u16* gB1,
                                      u16* sA, u16* sB,
                                      u16* dA0, u16* dA1, u16* dB0, u16* dB1,
                                      int wm, int wn, int lm, int lg, int sx,
                                      f32x4 acc[4][4])
{
    __syncthreads();                 // previous iter's readers done
    ld16(gA0, dA0);
    ld16(gA1, dA1);
    ld16(gB0, dB0);
    ld16(gB1, dB1);
    __syncthreads();                 // drains vmcnt for global_load_lds

    s16x8 af[4], bf[4];
    const int co = (lg ^ sx) * 8;
#pragma unroll
    for (int i = 0; i < 4; i++) {
        af[i] = *(const s16x8*)&sA[(wm + i * 16 + lm) * 32 + co];
        bf[i] = *(const s16x8*)&sB[(wn + i * 16 + lm) * 32 + co];
    }
#pragma unroll
    for (int i = 0; i < 4; i++)
#pragma unroll
        for (int j = 0; j < 4; j++)
            acc[i][j] = __builtin_amdgcn_mfma_f32_16x16x32_bf16(af[i], bf[j], acc[i][j], 0, 0, 0);
}

// Standard B^T-form core: C[m][n] = sum_k A[m][k]*B[n][k], contiguous K.
__device__ __forceinline__ void gemm_core(const u16* A, long lda, const u16* B, long ldb,
                                          int m0, int n0, int kEnd,
                                          f32x4 acc[4][4], u16* sA, u16* sB)
{
    const int t    = threadIdx.x;
    const int lane = t & 63;
    const int wave = t >> 6;
    const int wm   = (wave & 1) << 6;
    const int wn   = (wave >> 1) << 6;
    const int lm   = lane & 15;
    const int lg   = lane >> 4;
    const int sx   = (lm >> 1) & 3;
    const int sr   = t >> 2;                              // staging row 0..63
    const int sc   = (((t & 3) ^ ((t >> 3) & 3)) << 3);   // swizzled chunk
    const u16* gA0 = A + (long)(m0 + sr) * lda + sc;
    const u16* gA1 = A + (long)(m0 + 64 + sr) * lda + sc;
    const u16* gB0 = B + (long)(n0 + sr) * ldb + sc;
    const u16* gB1 = B + (long)(n0 + 64 + sr) * ldb + sc;
    u16* dA0 = sA + t * 8;  u16* dA1 = sA + 2048 + t * 8;
    u16* dB0 = sB + t * 8;  u16* dB1 = sB + 2048 + t * 8;

    for (int k0 = 0; k0 < kEnd; k0 += 32)
        kstep(gA0 + k0, gA1 + k0, gB0 + k0, gB1 + k0,
              sA, sB, dA0, dA1, dB0, dB1, wm, wn, lm, lg, sx, acc);
}

// ---------------------------------------------------------------------------
// Conversions
// ---------------------------------------------------------------------------
__global__ void convert_x(const float* __restrict__ X, u16* __restrict__ Xb) {
    long idx = ((long)blockIdx.x * 256 + threadIdx.x) * 4;
    f32x4 v = *(const f32x4*)&X[idx];
    s16x4 o;
    o.x = (short)f2bf(v.x); o.y = (short)f2bf(v.y);
    o.z = (short)f2bf(v.z); o.w = (short)f2bf(v.w);
    *(s16x4*)&Xb[idx] = o;
}

// W[k][n] fp32 -> Wt[n][k] bf16, 64x64 LDS tile transpose. grid (256, 3)
__global__ void convert_w(const float* __restrict__ Wk, const float* __restrict__ Wq,
                          const float* __restrict__ Wv,
                          u16* __restrict__ Wkt, u16* __restrict__ Wqt, u16* __restrict__ Wvt) {
    const float* W; u16* O;
    if (blockIdx.y == 0)      { W = Wk; O = Wkt; }
    else if (blockIdx.y == 1) { W = Wq; O = Wqt; }
    else                      { W = Wv; O = Wvt; }
    __shared__ u16 tile[64][65];
    int k0 = (blockIdx.x >> 4) << 6, n0 = (blockIdx.x & 15) << 6;
    int t = threadIdx.x;
    int rr = t >> 4, cc = (t & 15) << 2;
#pragma unroll
    for (int i = 0; i < 4; i++) {
        int row = rr + i * 16;
        f32x4 v = *(const f32x4*)&W[(long)(k0 + row) * 1024 + n0 + cc];
        tile[row][cc + 0] = f2bf(v.x); tile[row][cc + 1] = f2bf(v.y);
        tile[row][cc + 2] = f2bf(v.z); tile[row][cc + 3] = f2bf(v.w);
    }
    __syncthreads();
#pragma unroll
    for (int i = 0; i < 4; i++) {
        int row = rr + i * 16;
        s16x4 pk;
        pk.x = (short)tile[cc + 0][row]; pk.y = (short)tile[cc + 1][row];
        pk.z = (short)tile[cc + 2][row]; pk.w = (short)tile[cc + 3][row];
        *(s16x4*)&O[(long)(n0 + row) * 1024 + k0 + cc] = pk;
    }
}

// ---------------------------------------------------------------------------
// All three projections in one launch. grid 3072: z = blockIdx.x>>10 picks
// Q (0), K (1), V (2, written transposed Vt[b][a][s]).
// ---------------------------------------------------------------------------
__global__ __launch_bounds__(256, 2) void proj_all(const u16* __restrict__ X,
                                                   const u16* __restrict__ Wqt,
                                                   const u16* __restrict__ Wkt,
                                                   const u16* __restrict__ Wvt,
                                                   u16* __restrict__ Qb,
                                                   u16* __restrict__ Kb,
                                                   u16* __restrict__ Vt) {
    __shared__ u16 sA[4096], sB[4096];
    int z = blockIdx.x >> 10;
    int q = blockIdx.x & 1023;
    int m0 = (q >> 3) * 128, n0 = (q & 7) * 128;
    const u16* Wt = (z == 0) ? Wqt : (z == 1) ? Wkt : Wvt;
    f32x4 acc[4][4] = {};
    gemm_core(X, 1024, Wt, 1024, m0, n0, 1024, acc, sA, sB);

    int lane = threadIdx.x & 63, wave = threadIdx.x >> 6;
    int wm = (wave & 1) << 6, wn = (wave >> 1) << 6, lm = lane & 15, lg = lane >> 4;
    if (z < 2) {
        u16* O = (z == 0) ? Qb : Kb;
#pragma unroll
        for (int i = 0; i < 4; i++)
#pragma unroll
            for (int j = 0; j < 4; j++)
#pragma unroll
                for (int r = 0; r < 4; r++) {
                    int row = m0 + wm + i * 16 + lg * 4 + r;
                    int col = n0 + wn + j * 16 + lm;
                    O[(long)row * 1024 + col] = f2bf(acc[i][j][r]);
                }
    } else {
#pragma unroll
        for (int i = 0; i < 4; i++)
#pragma unroll
            for (int j = 0; j < 4; j++) {
                int row0 = m0 + wm + i * 16 + lg * 4;
                int col  = n0 + wn + j * 16 + lm;
                int b = row0 >> 12, s = row0 & 4095;
                s16x4 pk;
                pk.x = (short)f2bf(acc[i][j][0]); pk.y = (short)f2bf(acc[i][j][1]);
                pk.z = (short)f2bf(acc[i][j][2]); pk.w = (short)f2bf(acc[i][j][3]);
                *(s16x4*)&Vt[(long)b * 4194304 + (long)col * 4096 + s] = pk;
            }
    }
}

// ---------------------------------------------------------------------------
// S = (Q K^T)/32, causal; lower-triangular tiles only, PACKED storage:
// tile (b,it,jt) at ((b*528 + it*(it+1)/2 + jt) * 16384) f16 elements,
// row-major 128x128 inside the tile. grid 4*528.
// ---------------------------------------------------------------------------
__global__ __launch_bounds__(256, 2) void sgemm_causal(const u16* __restrict__ Q,
                                                       const u16* __restrict__ K,
                                                       u16* __restrict__ S) {
    __shared__ u16 sA[4096], sB[4096];
    int b  = blockIdx.x / 528;
    int tt = blockIdx.x % 528;
    int it = (int)((sqrtf(8.0f * tt + 1.0f) - 1.0f) * 0.5f);
    while ((it + 1) * (it + 2) / 2 <= tt) ++it;
    while (it * (it + 1) / 2 > tt) --it;
    int jt = tt - it * (it + 1) / 2;

    const u16* A  = Q + (long)b * 4194304;
    const u16* Bt = K + (long)b * 4194304;
    f32x4 acc[4][4] = {};
    gemm_core(A, 1024, Bt, 1024, it * 128, jt * 128, 1024, acc, sA, sB);

    u16* Sp = S + (long)(b * 528 + tt) * 16384;
    int lane = threadIdx.x & 63, wave = threadIdx.x >> 6;
    int wm = (wave & 1) << 6, wn = (wave >> 1) << 6, lm = lane & 15, lg = lane >> 4;
#pragma unroll
    for (int i = 0; i < 4; i++)
#pragma unroll
        for (int j = 0; j < 4; j++)
#pragma unroll
            for (int r = 0; r < 4; r++) {
                int ri = wm + i * 16 + lg * 4 + r;
                int cj = wn + j * 16 + lm;
                float v = acc[i][j][r] * 0.03125f;
                if (jt * 128 + cj > it * 128 + ri) v = -30000.0f;
                Sp[ri * 128 + cj] = __half_as_ushort(__float2half(v));
            }
}

// ---------------------------------------------------------------------------
// Row softmax over packed tiles: one wave per row, f16 in -> bf16 in place,
// stores 1/l. grid 4096 (16384 rows total).
// ---------------------------------------------------------------------------
__global__ __launch_bounds__(256) void row_softmax(u16* __restrict__ S,
                                                   float* __restrict__ inv_l) {
    int wave = threadIdx.x >> 6, lane = threadIdx.x & 63;
    int gr = blockIdx.x * 4 + wave;         // 0..16383
    int b  = gr >> 12;
    int r  = gr & 4095;
    int it = r >> 7, ri = r & 127;
    u16* base = S + (long)(b * 528 + it * (it + 1) / 2) * 16384 + ri * 128;
    int c = lane * 2;

    float m = -1e30f;
    for (int jt = 0; jt <= it; jt++) {
        u32 v = *(const u32*)&base[jt * 16384 + c];
        float a0 = __half2float(__ushort_as_half((u16)(v & 0xffff)));
        float a1 = __half2float(__ushort_as_half((u16)(v >> 16)));
        m = fmaxf(m, fmaxf(a0, a1));
    }
#pragma unroll
    for (int o = 32; o; o >>= 1) m = fmaxf(m, __shfl_xor(m, o, 64));

    const float LOG2E = 1.44269504088896f;
    float l = 0.0f;
    for (int jt = 0; jt <= it; jt++) {
        u32 v = *(const u32*)&base[jt * 16384 + c];
        float a0 = __half2float(__ushort_as_half((u16)(v & 0xffff)));
        float a1 = __half2float(__ushort_as_half((u16)(v >> 16)));
        float p0 = exp2f((a0 - m) * LOG2E);
        float p1 = exp2f((a1 - m) * LOG2E);
        u32 o = (u32)f2bf(p0) | ((u32)f2bf(p1) << 16);
        *(u32*)&base[jt * 16384 + c] = o;
        l += p0 + p1;
    }
#pragma unroll
    for (int o = 32; o; o >>= 1) l += __shfl_xor(l, o, 64);
    if (lane == 0) inv_l[gr] = 1.0f / l;
}

// ---------------------------------------------------------------------------
// O = P @ V (packed P tiles, Vt), scaled by 1/l, fp32 out. grid 1024,
// heaviest it first: it = 31 - (g>>5), rem decodes (b, at).
// ---------------------------------------------------------------------------
__global__ __launch_bounds__(256, 2) void pv_gemm(const u16* __restrict__ P,
                                                  const u16* __restrict__ Vt,
                                                  const float* __restrict__ inv_l,
                                                  float* __restrict__ Out) {
    __shared__ u16 sA[4096], sB[4096];
    int g   = blockIdx.x;
    int it  = 31 - (g >> 5);
    int rem = g & 31;
    int b   = rem >> 3;
    int at  = rem & 7;

    const int t    = threadIdx.x;
    const int lane = t & 63;
    const int wave = t >> 6;
    const int wm   = (wave & 1) << 6;
    const int wn   = (wave >> 1) << 6;
    const int lm   = lane & 15;
    const int lg   = lane >> 4;
    const int sx   = (lm >> 1) & 3;
    const int sr   = t >> 2;
    const int sc   = (((t & 3) ^ ((t >> 3) & 3)) << 3);

    const u16* Pbase = P + (long)(b * 528 + it * (it + 1) / 2) * 16384;
    const u16* gA0 = Pbase + sr * 128 + sc;
    const u16* gA1 = gA0 + 64 * 128;
    const u16* gB0 = Vt + (long)b * 4194304 + (long)(at * 128 + sr) * 4096 + sc;
    const u16* gB1 = gB0 + (long)64 * 4096;
    u16* dA0 = sA + t * 8;  u16* dA1 = sA + 2048 + t * 8;
    u16* dB0 = sB + t * 8;  u16* dB1 = sB + 2048 + t * 8;

    f32x4 acc[4][4] = {};
    for (int jt = 0; jt <= it; jt++) {
        long aoff = (long)jt * 16384;
        long boff = (long)jt * 128;
#pragma unroll
        for (int kk = 0; kk < 128; kk += 32)
            kstep(gA0 + aoff + kk, gA1 + aoff + kk, gB0 + boff + kk, gB1 + boff + kk,
                  sA, sB, dA0, dA1, dB0, dB1, wm, wn, lm, lg, sx, acc);
    }

#pragma unroll
    for (int i = 0; i < 4; i++)
#pragma unroll
        for (int j = 0; j < 4; j++)
#pragma unroll
            for (int r = 0; r < 4; r++) {
                int gi = it * 128 + wm + i * 16 + lg * 4 + r;
                int ga = at * 128 + wn + j * 16 + lm;
                Out[((long)b * 4096 + gi) * 1024 + ga] = acc[i][j][r] * inv_l[b * 4096 + gi];
            }
}

// ---------------------------------------------------------------------------
// Workspace layout (bytes):
//   Qb   [0,          33554432)   bf16 Q, [b][s][a]
//   Kb   [33554432,   67108864)   bf16 K
//   Vt   [67108864,  100663296)   bf16 V transposed [b][a][s]
//   invl [100663296, 100728832)   fp32 1/l per row
//   Xb   [100728832, 134283264)   bf16 X          (dead after proj_all)
//   Wqt/Wkt/Wvt [134283264, 140574720)            (dead after proj_all)
//   S    [100728832, 169934848)   packed tri tiles, OVERLAYS Xb+W
// Peak 169.9 MB — under the 174.1 MB the R0 per-batch path proved available.
// ---------------------------------------------------------------------------
extern "C" void kernel_launch(void* const* d_in, const int* in_sizes, int n_in,
                              void* d_out, int out_size, void* d_ws, size_t ws_size,
                              hipStream_t stream) {
    const float* X  = (const float*)d_in[0];
    const float* Wk = (const float*)d_in[1];
    const float* Wq = (const float*)d_in[2];
    const float* Wv = (const float*)d_in[3];
    float* Out = (float*)d_out;

    char* w = (char*)d_ws;
    u16*   Qb   = (u16*)(w);
    u16*   Kb   = (u16*)(w + 33554432);
    u16*   Vt   = (u16*)(w + 67108864);
    float* invl = (float*)(w + 100663296);
    u16*   Xb   = (u16*)(w + 100728832);
    u16*   Wqt  = (u16*)(w + 134283264);
    u16*   Wkt  = (u16*)(w + 136380416);
    u16*   Wvt  = (u16*)(w + 138477568);
    u16*   S    = (u16*)(w + 100728832);   // overlays Xb + W after projections

    convert_x<<<16384, 256, 0, stream>>>(X, Xb);
    convert_w<<<dim3(256, 3), 256, 0, stream>>>(Wk, Wq, Wv, Wkt, Wqt, Wvt);
    proj_all<<<3072, 256, 0, stream>>>(Xb, Wqt, Wkt, Wvt, Qb, Kb, Vt);
    sgemm_causal<<<4 * 528, 256, 0, stream>>>(Qb, Kb, S);
    row_softmax<<<4096, 256, 0, stream>>>(S, invl);
    pv_gemm<<<1024, 256, 0, stream>>>(S, Vt, invl, Out);
}

// Round 3
// 496.467 us; speedup vs baseline: 1.5433x; 1.0268x over previous
//
#include <hip/hip_runtime.h>
#include <hip/hip_fp16.h>

typedef __attribute__((ext_vector_type(4))) float f32x4;
typedef __attribute__((ext_vector_type(8))) short s16x8;
typedef __attribute__((ext_vector_type(4))) short s16x4;
typedef unsigned short u16;
typedef unsigned int u32;

__device__ __forceinline__ u16 f2bf(float f) {
    union { float f; unsigned u; } x; x.f = f;
    return (u16)((x.u + 0x7fffu + ((x.u >> 16) & 1u)) >> 16);
}

__device__ __forceinline__ void ld16(const void* g, void* l) {
    __builtin_amdgcn_global_load_lds(
        (const __attribute__((address_space(1))) unsigned int*)g,
        (__attribute__((address_space(3))) unsigned int*)l, 16, 0, 0);
}

// ---------------------------------------------------------------------------
// One 32-wide K-step of a 128x256 output tile: stage A (128x32) + B0 + B1
// (128x32 each) via global_load_lds w=16, then 32 MFMA per wave (64 per acc
// set per block? -> 128 MFMA/block-kstep). XOR swizzle (proven 0-conflict in
// R1): staging chunk (t&3)^((t>>3)&3); readers use co = (lg ^ ((lm>>1)&3))*8.
// ---------------------------------------------------------------------------
__device__ __forceinline__ void kstep2(const u16* gA0, const u16* gA1,
                                       const u16* gB0, const u16* gB1,
                                       const u16* gC0, const u16* gC1,
                                       u16* sA, u16* sB,
                                       int wm, int wn, int lm, int lg, int sx,
                                       f32x4 acc0[4][4], f32x4 acc1[4][4])
{
    const int t = threadIdx.x;
    u16* dA0 = sA + t * 8;        u16* dA1 = sA + 2048 + t * 8;
    u16* dB0 = sB + t * 8;        u16* dB1 = sB + 2048 + t * 8;
    u16* dC0 = sB + 4096 + t * 8; u16* dC1 = sB + 6144 + t * 8;

    __syncthreads();                 // previous iter's readers done
    ld16(gA0, dA0); ld16(gA1, dA1);
    ld16(gB0, dB0); ld16(gB1, dB1);
    ld16(gC0, dC0); ld16(gC1, dC1);
    __syncthreads();                 // drains vmcnt for global_load_lds

    s16x8 af[4], bf[4], cf[4];
    const int co = (lg ^ sx) * 8;
#pragma unroll
    for (int i = 0; i < 4; i++) {
        af[i] = *(const s16x8*)&sA[(wm + i * 16 + lm) * 32 + co];
        bf[i] = *(const s16x8*)&sB[(wn + i * 16 + lm) * 32 + co];
        cf[i] = *(const s16x8*)&sB[4096 + (wn + i * 16 + lm) * 32 + co];
    }
#pragma unroll
    for (int i = 0; i < 4; i++)
#pragma unroll
        for (int j = 0; j < 4; j++) {
            acc0[i][j] = __builtin_amdgcn_mfma_f32_16x16x32_bf16(af[i], bf[j], acc0[i][j], 0, 0, 0);
            acc1[i][j] = __builtin_amdgcn_mfma_f32_16x16x32_bf16(af[i], cf[j], acc1[i][j], 0, 0, 0);
        }
}

// Contiguous-K core: C[m][n] = sum_k A[m][k]*B[n][k] for n in two 128-tiles.
__device__ __forceinline__ void gemm_core2(const u16* A, long lda,
                                           const u16* B0, const u16* B1, long ldb,
                                           int m0, int kEnd,
                                           f32x4 acc0[4][4], f32x4 acc1[4][4],
                                           u16* sA, u16* sB)
{
    const int t    = threadIdx.x;
    const int lane = t & 63;
    const int wave = t >> 6;
    const int wm   = (wave & 1) << 6;
    const int wn   = (wave >> 1) << 6;
    const int lm   = lane & 15;
    const int lg   = lane >> 4;
    const int sx   = (lm >> 1) & 3;
    const int sr   = t >> 2;
    const int sc   = (((t & 3) ^ ((t >> 3) & 3)) << 3);
    const u16* gA0 = A + (long)(m0 + sr) * lda + sc;
    const u16* gA1 = A + (long)(m0 + 64 + sr) * lda + sc;
    const u16* gB0 = B0 + (long)sr * ldb + sc;
    const u16* gB1 = B0 + (long)(64 + sr) * ldb + sc;
    const u16* gC0 = B1 + (long)sr * ldb + sc;
    const u16* gC1 = B1 + (long)(64 + sr) * ldb + sc;

    for (int k0 = 0; k0 < kEnd; k0 += 32)
        kstep2(gA0 + k0, gA1 + k0, gB0 + k0, gB1 + k0, gC0 + k0, gC1 + k0,
               sA, sB, wm, wn, lm, lg, sx, acc0, acc1);
}

// ---------------------------------------------------------------------------
// Conversions
// ---------------------------------------------------------------------------
__global__ void convert_x(const float* __restrict__ X, u16* __restrict__ Xb) {
    long idx = ((long)blockIdx.x * 256 + threadIdx.x) * 4;
    f32x4 v = *(const f32x4*)&X[idx];
    s16x4 o;
    o.x = (short)f2bf(v.x); o.y = (short)f2bf(v.y);
    o.z = (short)f2bf(v.z); o.w = (short)f2bf(v.w);
    *(s16x4*)&Xb[idx] = o;
}

// W[k][n] fp32 -> Wt[n][k] bf16, 64x64 LDS tile transpose. grid (256, 3)
__global__ void convert_w(const float* __restrict__ Wk, const float* __restrict__ Wq,
                          const float* __restrict__ Wv,
                          u16* __restrict__ Wkt, u16* __restrict__ Wqt, u16* __restrict__ Wvt) {
    const float* W; u16* O;
    if (blockIdx.y == 0)      { W = Wk; O = Wkt; }
    else if (blockIdx.y == 1) { W = Wq; O = Wqt; }
    else                      { W = Wv; O = Wvt; }
    __shared__ u16 tile[64][65];
    int k0 = (blockIdx.x >> 4) << 6, n0 = (blockIdx.x & 15) << 6;
    int t = threadIdx.x;
    int rr = t >> 4, cc = (t & 15) << 2;
#pragma unroll
    for (int i = 0; i < 4; i++) {
        int row = rr + i * 16;
        f32x4 v = *(const f32x4*)&W[(long)(k0 + row) * 1024 + n0 + cc];
        tile[row][cc + 0] = f2bf(v.x); tile[row][cc + 1] = f2bf(v.y);
        tile[row][cc + 2] = f2bf(v.z); tile[row][cc + 3] = f2bf(v.w);
    }
    __syncthreads();
#pragma unroll
    for (int i = 0; i < 4; i++) {
        int row = rr + i * 16;
        s16x4 pk;
        pk.x = (short)tile[cc + 0][row]; pk.y = (short)tile[cc + 1][row];
        pk.z = (short)tile[cc + 2][row]; pk.w = (short)tile[cc + 3][row];
        *(s16x4*)&O[(long)(n0 + row) * 1024 + k0 + cc] = pk;
    }
}

// ---------------------------------------------------------------------------
// All three projections, 128x256 output per block. grid 1536:
// z = bx>>9 (Q/K/V), m0 = ((bx&511)>>2)*128, n-pair = (bx&3)*256.
// ---------------------------------------------------------------------------
__global__ __launch_bounds__(256, 2) void proj_all(const u16* __restrict__ X,
                                                   const u16* __restrict__ Wqt,
                                                   const u16* __restrict__ Wkt,
                                                   const u16* __restrict__ Wvt,
                                                   u16* __restrict__ Qb,
                                                   u16* __restrict__ Kb,
                                                   u16* __restrict__ Vt) {
    __shared__ u16 sA[4096], sB[8192];
    int z   = blockIdx.x >> 9;
    int rem = blockIdx.x & 511;
    int m0  = (rem >> 2) * 128;
    int n0  = (rem & 3) * 256;
    const u16* Wt = (z == 0) ? Wqt : (z == 1) ? Wkt : Wvt;

    f32x4 acc0[4][4] = {}, acc1[4][4] = {};
    gemm_core2(X, 1024, Wt + (long)n0 * 1024, Wt + (long)(n0 + 128) * 1024, 1024,
               m0, 1024, acc0, acc1, sA, sB);

    int lane = threadIdx.x & 63, wave = threadIdx.x >> 6;
    int wm = (wave & 1) << 6, wn = (wave >> 1) << 6, lm = lane & 15, lg = lane >> 4;
    if (z < 2) {
        u16* O = (z == 0) ? Qb : Kb;
#pragma unroll
        for (int i = 0; i < 4; i++)
#pragma unroll
            for (int j = 0; j < 4; j++)
#pragma unroll
                for (int r = 0; r < 4; r++) {
                    int row = m0 + wm + i * 16 + lg * 4 + r;
                    int col = n0 + wn + j * 16 + lm;
                    O[(long)row * 1024 + col]       = f2bf(acc0[i][j][r]);
                    O[(long)row * 1024 + col + 128] = f2bf(acc1[i][j][r]);
                }
    } else {
#pragma unroll
        for (int i = 0; i < 4; i++)
#pragma unroll
            for (int j = 0; j < 4; j++) {
                int row0 = m0 + wm + i * 16 + lg * 4;
                int col  = n0 + wn + j * 16 + lm;
                int b = row0 >> 12, s = row0 & 4095;
                s16x4 p0, p1;
                p0.x = (short)f2bf(acc0[i][j][0]); p0.y = (short)f2bf(acc0[i][j][1]);
                p0.z = (short)f2bf(acc0[i][j][2]); p0.w = (short)f2bf(acc0[i][j][3]);
                p1.x = (short)f2bf(acc1[i][j][0]); p1.y = (short)f2bf(acc1[i][j][1]);
                p1.z = (short)f2bf(acc1[i][j][2]); p1.w = (short)f2bf(acc1[i][j][3]);
                *(s16x4*)&Vt[(long)b * 4194304 + (long)col * 4096 + s]         = p0;
                *(s16x4*)&Vt[(long)b * 4194304 + (long)(col + 128) * 4096 + s] = p1;
            }
    }
}

// ---------------------------------------------------------------------------
// S = (Q K^T)/32, causal, packed lower-tri tiles (f16). Each block computes a
// jt-PAIR (jt0=2*jp, jt1=jt0+1); lone tile for even it computes a discarded
// second tile (memory-safe: jt1 <= 31 always). 272 blocks/batch, grid 1088.
// cum(it) = ((it+1)^2)>>2 pairs before row it.
// ---------------------------------------------------------------------------
__global__ __launch_bounds__(256, 2) void sgemm_causal(const u16* __restrict__ Q,
                                                       const u16* __restrict__ K,
                                                       u16* __restrict__ S) {
    __shared__ u16 sA[4096], sB[8192];
    int b  = blockIdx.x / 272;
    int tt = blockIdx.x % 272;
    int it = (int)(2.0f * sqrtf((float)tt + 1.0f)) - 1;
    if (it > 31) it = 31;
    if (it < 0) it = 0;
    while (it < 31 && (((it + 2) * (it + 2)) >> 2) <= tt) ++it;
    while (it > 0 && (((it + 1) * (it + 1)) >> 2) > tt) --it;
    int jp  = tt - (((it + 1) * (it + 1)) >> 2);
    int jt0 = jp * 2, jt1 = jt0 + 1;
    bool valid1 = (jt1 <= it);

    const u16* A  = Q + (long)b * 4194304;
    const u16* Kb = K + (long)b * 4194304;
    f32x4 acc0[4][4] = {}, acc1[4][4] = {};
    gemm_core2(A, 1024, Kb + (long)jt0 * 131072, Kb + (long)jt1 * 131072, 1024,
               it * 128, 1024, acc0, acc1, sA, sB);

    long tribase = (long)(b * 528 + ((it * (it + 1)) >> 1));
    u16* Sp0 = S + (tribase + jt0) * 16384;
    u16* Sp1 = S + (tribase + jt1) * 16384;
    int lane = threadIdx.x & 63, wave = threadIdx.x >> 6;
    int wm = (wave & 1) << 6, wn = (wave >> 1) << 6, lm = lane & 15, lg = lane >> 4;
#pragma unroll
    for (int i = 0; i < 4; i++)
#pragma unroll
        for (int j = 0; j < 4; j++)
#pragma unroll
            for (int r = 0; r < 4; r++) {
                int ri = wm + i * 16 + lg * 4 + r;
                int cj = wn + j * 16 + lm;
                int gi = it * 128 + ri;
                float v0 = acc0[i][j][r] * 0.03125f;
                if (jt0 * 128 + cj > gi) v0 = -30000.0f;
                Sp0[ri * 128 + cj] = __half_as_ushort(__float2half(v0));
                if (valid1) {
                    float v1 = acc1[i][j][r] * 0.03125f;
                    if (jt1 * 128 + cj > gi) v1 = -30000.0f;
                    Sp1[ri * 128 + cj] = __half_as_ushort(__float2half(v1));
                }
            }
}

// ---------------------------------------------------------------------------
// Row softmax over packed tiles: one wave per row, f16 -> bf16 in place + 1/l.
// ---------------------------------------------------------------------------
__global__ __launch_bounds__(256) void row_softmax(u16* __restrict__ S,
                                                   float* __restrict__ inv_l) {
    int wave = threadIdx.x >> 6, lane = threadIdx.x & 63;
    int gr = blockIdx.x * 4 + wave;
    int b  = gr >> 12;
    int r  = gr & 4095;
    int it = r >> 7, ri = r & 127;
    u16* base = S + (long)(b * 528 + ((it * (it + 1)) >> 1)) * 16384 + ri * 128;
    int c = lane * 2;

    float m = -1e30f;
    for (int jt = 0; jt <= it; jt++) {
        u32 v = *(const u32*)&base[jt * 16384 + c];
        float a0 = __half2float(__ushort_as_half((u16)(v & 0xffff)));
        float a1 = __half2float(__ushort_as_half((u16)(v >> 16)));
        m = fmaxf(m, fmaxf(a0, a1));
    }
#pragma unroll
    for (int o = 32; o; o >>= 1) m = fmaxf(m, __shfl_xor(m, o, 64));

    const float LOG2E = 1.44269504088896f;
    float l = 0.0f;
    for (int jt = 0; jt <= it; jt++) {
        u32 v = *(const u32*)&base[jt * 16384 + c];
        float a0 = __half2float(__ushort_as_half((u16)(v & 0xffff)));
        float a1 = __half2float(__ushort_as_half((u16)(v >> 16)));
        float p0 = exp2f((a0 - m) * LOG2E);
        float p1 = exp2f((a1 - m) * LOG2E);
        u32 o = (u32)f2bf(p0) | ((u32)f2bf(p1) << 16);
        *(u32*)&base[jt * 16384 + c] = o;
        l += p0 + p1;
    }
#pragma unroll
    for (int o = 32; o; o >>= 1) l += __shfl_xor(l, o, 64);
    if (lane == 0) inv_l[gr] = 1.0f / l;
}

// ---------------------------------------------------------------------------
// O = P @ V: 128 rows x 256 cols (at-pair) per block. grid 512, balanced:
// g<256 -> it=31-(g>>4); else it=(g-256)>>4, so co-resident block pairs sum
// to constant K-work. rem=g&15: b=rem>>2, atp=rem&3.
// ---------------------------------------------------------------------------
__global__ __launch_bounds__(256, 2) void pv_gemm(const u16* __restrict__ P,
                                                  const u16* __restrict__ Vt,
                                                  const float* __restrict__ inv_l,
                                                  float* __restrict__ Out) {
    __shared__ u16 sA[4096], sB[8192];
    int g  = blockIdx.x;
    int it = (g < 256) ? (31 - (g >> 4)) : ((g - 256) >> 4);
    int rem = g & 15;
    int b   = rem >> 2;
    int atp = rem & 3;

    const int t    = threadIdx.x;
    const int lane = t & 63;
    const int wave = t >> 6;
    const int wm   = (wave & 1) << 6;
    const int wn   = (wave >> 1) << 6;
    const int lm   = lane & 15;
    const int lg   = lane >> 4;
    const int sx   = (lm >> 1) & 3;
    const int sr   = t >> 2;
    const int sc   = (((t & 3) ^ ((t >> 3) & 3)) << 3);

    const u16* Pbase = P + (long)(b * 528 + ((it * (it + 1)) >> 1)) * 16384;
    const u16* gA0 = Pbase + sr * 128 + sc;
    const u16* gA1 = gA0 + 64 * 128;
    const u16* gB0 = Vt + (long)b * 4194304 + (long)(atp * 256 + sr) * 4096 + sc;
    const u16* gB1 = gB0 + (long)64 * 4096;
    const u16* gC0 = gB0 + (long)128 * 4096;
    const u16* gC1 = gB0 + (long)192 * 4096;

    f32x4 acc0[4][4] = {}, acc1[4][4] = {};
    for (int jt = 0; jt <= it; jt++) {
        long aoff = (long)jt * 16384;
        long boff = (long)jt * 128;
#pragma unroll
        for (int kk = 0; kk < 128; kk += 32)
            kstep2(gA0 + aoff + kk, gA1 + aoff + kk,
                   gB0 + boff + kk, gB1 + boff + kk,
                   gC0 + boff + kk, gC1 + boff + kk,
                   sA, sB, wm, wn, lm, lg, sx, acc0, acc1);
    }

#pragma unroll
    for (int i = 0; i < 4; i++)
#pragma unroll
        for (int j = 0; j < 4; j++)
#pragma unroll
            for (int r = 0; r < 4; r++) {
                int gi = it * 128 + wm + i * 16 + lg * 4 + r;
                int ga = atp * 256 + wn + j * 16 + lm;
                float s = inv_l[b * 4096 + gi];
                Out[((long)b * 4096 + gi) * 1024 + ga]       = acc0[i][j][r] * s;
                Out[((long)b * 4096 + gi) * 1024 + ga + 128] = acc1[i][j][r] * s;
            }
}

// ---------------------------------------------------------------------------
// Workspace layout (bytes): same as R1.
//   Qb   [0,          33554432)
//   Kb   [33554432,   67108864)
//   Vt   [67108864,  100663296)
//   invl [100663296, 100728832)
//   Xb   [100728832, 134283264)   (dead after proj_all)
//   Wqt/Wkt/Wvt [134283264, 140574720)  (dead after proj_all)
//   S    [100728832, 169934848)   packed tri tiles, overlays Xb+W
// ---------------------------------------------------------------------------
extern "C" void kernel_launch(void* const* d_in, const int* in_sizes, int n_in,
                              void* d_out, int out_size, void* d_ws, size_t ws_size,
                              hipStream_t stream) {
    const float* X  = (const float*)d_in[0];
    const float* Wk = (const float*)d_in[1];
    const float* Wq = (const float*)d_in[2];
    const float* Wv = (const float*)d_in[3];
    float* Out = (float*)d_out;

    char* w = (char*)d_ws;
    u16*   Qb   = (u16*)(w);
    u16*   Kb   = (u16*)(w + 33554432);
    u16*   Vt   = (u16*)(w + 67108864);
    float* invl = (float*)(w + 100663296);
    u16*   Xb   = (u16*)(w + 100728832);
    u16*   Wqt  = (u16*)(w + 134283264);
    u16*   Wkt  = (u16*)(w + 136380416);
    u16*   Wvt  = (u16*)(w + 138477568);
    u16*   S    = (u16*)(w + 100728832);

    convert_x<<<16384, 256, 0, stream>>>(X, Xb);
    convert_w<<<dim3(256, 3), 256, 0, stream>>>(Wk, Wq, Wv, Wkt, Wqt, Wvt);
    proj_all<<<1536, 256, 0, stream>>>(Xb, Wqt, Wkt, Wvt, Qb, Kb, Vt);
    sgemm_causal<<<1088, 256, 0, stream>>>(Qb, Kb, S);
    row_softmax<<<4096, 256, 0, stream>>>(S, invl);
    pv_gemm<<<512, 256, 0, stream>>>(S, Vt, invl, Out);
}

// Round 4
// 491.060 us; speedup vs baseline: 1.5603x; 1.0110x over previous
//
#include <hip/hip_runtime.h>
#include <hip/hip_fp16.h>

typedef __attribute__((ext_vector_type(4))) float f32x4;
typedef __attribute__((ext_vector_type(8))) short s16x8;
typedef __attribute__((ext_vector_type(4))) short s16x4;
typedef unsigned short u16;
typedef unsigned int u32;

__device__ __forceinline__ u16 f2bf(float f) {
    union { float f; unsigned u; } x; x.f = f;
    return (u16)((x.u + 0x7fffu + ((x.u >> 16) & 1u)) >> 16);
}

// ---------------------------------------------------------------------------
// Pipelined 128x256 GEMM core. Per k-step (BK=32):
//   1. global_load (dwordx4) step k+1 -> regs        (latency hidden by 2+3)
//   2. ds_read frags from LDS buf[k&1] + 32 MFMA/wave
//   3. ds_write regs -> LDS buf[(k+1)&1]
//   4. ONE __syncthreads (vmcnt already drained by ds_write's data dep)
// XOR swizzle (0 conflicts, proven R1): staging thread t holds global chunk
// (t&3)^((t>>3)&3) of its row; readers use co = (lg ^ ((lm>>1)&3))*8.
// LDS: sA 2x8KB, sB 2x16KB = 48KB/block -> 2 blocks/CU.
// ---------------------------------------------------------------------------
template <typename AddrF>
__device__ __forceinline__ void gemm_pipe(int nsteps, AddrF addr,
                                          f32x4 acc0[4][4], f32x4 acc1[4][4],
                                          u16* sA, u16* sB)
{
    const int t    = threadIdx.x;
    const int lane = t & 63;
    const int wave = t >> 6;
    const int wm   = (wave & 1) << 6;
    const int wn   = (wave >> 1) << 6;
    const int lm   = lane & 15;
    const int lg   = lane >> 4;
    const int co   = (lg ^ ((lm >> 1) & 3)) * 8;

    const u16 *pa0, *pa1, *pb0, *pb1, *pc0, *pc1;
    addr(0, pa0, pa1, pb0, pb1, pc0, pc1);
    s16x8 ra0 = *(const s16x8*)pa0, ra1 = *(const s16x8*)pa1;
    s16x8 rb0 = *(const s16x8*)pb0, rb1 = *(const s16x8*)pb1;
    s16x8 rc0 = *(const s16x8*)pc0, rc1 = *(const s16x8*)pc1;
    {
        u16* wA = sA + t * 8;
        u16* wB = sB + t * 8;
        *(s16x8*)(wA)        = ra0; *(s16x8*)(wA + 2048) = ra1;
        *(s16x8*)(wB)        = rb0; *(s16x8*)(wB + 2048) = rb1;
        *(s16x8*)(wB + 4096) = rc0; *(s16x8*)(wB + 6144) = rc1;
    }
    __syncthreads();

    for (int k = 0; k < nsteps; ++k) {
        const int kb = k & 1, nb = kb ^ 1;
        const int kn = (k + 1 < nsteps) ? (k + 1) : k;   // tail: dup load, never read
        addr(kn, pa0, pa1, pb0, pb1, pc0, pc1);
        ra0 = *(const s16x8*)pa0; ra1 = *(const s16x8*)pa1;
        rb0 = *(const s16x8*)pb0; rb1 = *(const s16x8*)pb1;
        rc0 = *(const s16x8*)pc0; rc1 = *(const s16x8*)pc1;

        const u16* bA = sA + kb * 4096;
        const u16* bB = sB + kb * 8192;
        s16x8 af[4], bf[4], cf[4];
#pragma unroll
        for (int i = 0; i < 4; i++) {
            af[i] = *(const s16x8*)&bA[(wm + i * 16 + lm) * 32 + co];
            bf[i] = *(const s16x8*)&bB[(wn + i * 16 + lm) * 32 + co];
            cf[i] = *(const s16x8*)&bB[4096 + (wn + i * 16 + lm) * 32 + co];
        }
#pragma unroll
        for (int i = 0; i < 4; i++)
#pragma unroll
            for (int j = 0; j < 4; j++) {
                acc0[i][j] = __builtin_amdgcn_mfma_f32_16x16x32_bf16(af[i], bf[j], acc0[i][j], 0, 0, 0);
                acc1[i][j] = __builtin_amdgcn_mfma_f32_16x16x32_bf16(af[i], cf[j], acc1[i][j], 0, 0, 0);
            }

        u16* qA = sA + nb * 4096 + t * 8;
        u16* qB = sB + nb * 8192 + t * 8;
        *(s16x8*)(qA)        = ra0; *(s16x8*)(qA + 2048) = ra1;
        *(s16x8*)(qB)        = rb0; *(s16x8*)(qB + 2048) = rb1;
        *(s16x8*)(qB + 4096) = rc0; *(s16x8*)(qB + 6144) = rc1;
        __syncthreads();
    }
}

// ---------------------------------------------------------------------------
// Conversions
// ---------------------------------------------------------------------------
__global__ void convert_x(const float* __restrict__ X, u16* __restrict__ Xb) {
    long idx = ((long)blockIdx.x * 256 + threadIdx.x) * 4;
    f32x4 v = *(const f32x4*)&X[idx];
    s16x4 o;
    o.x = (short)f2bf(v.x); o.y = (short)f2bf(v.y);
    o.z = (short)f2bf(v.z); o.w = (short)f2bf(v.w);
    *(s16x4*)&Xb[idx] = o;
}

// W[k][n] fp32 -> Wt[n][k] bf16, 64x64 LDS tile transpose. grid (256, 3)
__global__ void convert_w(const float* __restrict__ Wk, const float* __restrict__ Wq,
                          const float* __restrict__ Wv,
                          u16* __restrict__ Wkt, u16* __restrict__ Wqt, u16* __restrict__ Wvt) {
    const float* W; u16* O;
    if (blockIdx.y == 0)      { W = Wk; O = Wkt; }
    else if (blockIdx.y == 1) { W = Wq; O = Wqt; }
    else                      { W = Wv; O = Wvt; }
    __shared__ u16 tile[64][65];
    int k0 = (blockIdx.x >> 4) << 6, n0 = (blockIdx.x & 15) << 6;
    int t = threadIdx.x;
    int rr = t >> 4, cc = (t & 15) << 2;
#pragma unroll
    for (int i = 0; i < 4; i++) {
        int row = rr + i * 16;
        f32x4 v = *(const f32x4*)&W[(long)(k0 + row) * 1024 + n0 + cc];
        tile[row][cc + 0] = f2bf(v.x); tile[row][cc + 1] = f2bf(v.y);
        tile[row][cc + 2] = f2bf(v.z); tile[row][cc + 3] = f2bf(v.w);
    }
    __syncthreads();
#pragma unroll
    for (int i = 0; i < 4; i++) {
        int row = rr + i * 16;
        s16x4 pk;
        pk.x = (short)tile[cc + 0][row]; pk.y = (short)tile[cc + 1][row];
        pk.z = (short)tile[cc + 2][row]; pk.w = (short)tile[cc + 3][row];
        *(s16x4*)&O[(long)(n0 + row) * 1024 + k0 + cc] = pk;
    }
}

// ---------------------------------------------------------------------------
// All three projections, 128x256 output per block. grid 1536.
// ---------------------------------------------------------------------------
__global__ __launch_bounds__(256, 2) void proj_all(const u16* __restrict__ X,
                                                   const u16* __restrict__ Wqt,
                                                   const u16* __restrict__ Wkt,
                                                   const u16* __restrict__ Wvt,
                                                   u16* __restrict__ Qb,
                                                   u16* __restrict__ Kb,
                                                   u16* __restrict__ Vt) {
    __shared__ u16 sA[8192], sB[16384];
    int z   = blockIdx.x >> 9;
    int rem = blockIdx.x & 511;
    int m0  = (rem >> 2) * 128;
    int n0  = (rem & 3) * 256;
    const u16* Wt = (z == 0) ? Wqt : (z == 1) ? Wkt : Wvt;

    const int t  = threadIdx.x;
    const int sr = t >> 2;
    const int sc = (((t & 3) ^ ((t >> 3) & 3)) << 3);
    const u16* gA0 = X + (long)(m0 + sr) * 1024 + sc;
    const u16* gA1 = gA0 + (long)64 * 1024;
    const u16* gB0 = Wt + (long)(n0 + sr) * 1024 + sc;
    const u16* gB1 = gB0 + (long)64 * 1024;
    const u16* gC0 = gB0 + (long)128 * 1024;
    const u16* gC1 = gB0 + (long)192 * 1024;

    f32x4 acc0[4][4] = {}, acc1[4][4] = {};
    auto addr = [&](int k, const u16*& a0, const u16*& a1, const u16*& b0,
                    const u16*& b1, const u16*& c0, const u16*& c1) {
        int off = k << 5;
        a0 = gA0 + off; a1 = gA1 + off;
        b0 = gB0 + off; b1 = gB1 + off;
        c0 = gC0 + off; c1 = gC1 + off;
    };
    gemm_pipe(32, addr, acc0, acc1, sA, sB);

    int lane = t & 63, wave = t >> 6;
    int wm = (wave & 1) << 6, wn = (wave >> 1) << 6, lm = lane & 15, lg = lane >> 4;
    if (z < 2) {
        u16* O = (z == 0) ? Qb : Kb;
#pragma unroll
        for (int i = 0; i < 4; i++)
#pragma unroll
            for (int j = 0; j < 4; j++)
#pragma unroll
                for (int r = 0; r < 4; r++) {
                    int row = m0 + wm + i * 16 + lg * 4 + r;
                    int col = n0 + wn + j * 16 + lm;
                    O[(long)row * 1024 + col]       = f2bf(acc0[i][j][r]);
                    O[(long)row * 1024 + col + 128] = f2bf(acc1[i][j][r]);
                }
    } else {
#pragma unroll
        for (int i = 0; i < 4; i++)
#pragma unroll
            for (int j = 0; j < 4; j++) {
                int row0 = m0 + wm + i * 16 + lg * 4;
                int col  = n0 + wn + j * 16 + lm;
                int b = row0 >> 12, s = row0 & 4095;
                s16x4 p0, p1;
                p0.x = (short)f2bf(acc0[i][j][0]); p0.y = (short)f2bf(acc0[i][j][1]);
                p0.z = (short)f2bf(acc0[i][j][2]); p0.w = (short)f2bf(acc0[i][j][3]);
                p1.x = (short)f2bf(acc1[i][j][0]); p1.y = (short)f2bf(acc1[i][j][1]);
                p1.z = (short)f2bf(acc1[i][j][2]); p1.w = (short)f2bf(acc1[i][j][3]);
                *(s16x4*)&Vt[(long)b * 4194304 + (long)col * 4096 + s]         = p0;
                *(s16x4*)&Vt[(long)b * 4194304 + (long)(col + 128) * 4096 + s] = p1;
            }
    }
}

// ---------------------------------------------------------------------------
// S = (Q K^T)/32, causal, packed lower-tri f16 tiles; jt-pairs per block.
// ---------------------------------------------------------------------------
__global__ __launch_bounds__(256, 2) void sgemm_causal(const u16* __restrict__ Q,
                                                       const u16* __restrict__ K,
                                                       u16* __restrict__ S) {
    __shared__ u16 sA[8192], sB[16384];
    int b  = blockIdx.x / 272;
    int tt = blockIdx.x % 272;
    int it = (int)(2.0f * sqrtf((float)tt + 1.0f)) - 1;
    if (it > 31) it = 31;
    if (it < 0) it = 0;
    while (it < 31 && (((it + 2) * (it + 2)) >> 2) <= tt) ++it;
    while (it > 0 && (((it + 1) * (it + 1)) >> 2) > tt) --it;
    int jp  = tt - (((it + 1) * (it + 1)) >> 2);
    int jt0 = jp * 2, jt1 = jt0 + 1;
    bool valid1 = (jt1 <= it);

    const u16* A  = Q + (long)b * 4194304;
    const u16* Kp = K + (long)b * 4194304;

    const int t  = threadIdx.x;
    const int sr = t >> 2;
    const int sc = (((t & 3) ^ ((t >> 3) & 3)) << 3);
    const u16* gA0 = A + (long)(it * 128 + sr) * 1024 + sc;
    const u16* gA1 = gA0 + (long)64 * 1024;
    const u16* gB0 = Kp + (long)(jt0 * 128 + sr) * 1024 + sc;
    const u16* gB1 = gB0 + (long)64 * 1024;
    const u16* gC0 = Kp + (long)(jt1 * 128 + sr) * 1024 + sc;
    const u16* gC1 = gC0 + (long)64 * 1024;

    f32x4 acc0[4][4] = {}, acc1[4][4] = {};
    auto addr = [&](int k, const u16*& a0, const u16*& a1, const u16*& b0,
                    const u16*& b1, const u16*& c0, const u16*& c1) {
        int off = k << 5;
        a0 = gA0 + off; a1 = gA1 + off;
        b0 = gB0 + off; b1 = gB1 + off;
        c0 = gC0 + off; c1 = gC1 + off;
    };
    gemm_pipe(32, addr, acc0, acc1, sA, sB);

    long tribase = (long)(b * 528 + ((it * (it + 1)) >> 1));
    u16* Sp0 = S + (tribase + jt0) * 16384;
    u16* Sp1 = S + (tribase + jt1) * 16384;
    int lane = t & 63, wave = t >> 6;
    int wm = (wave & 1) << 6, wn = (wave >> 1) << 6, lm = lane & 15, lg = lane >> 4;
#pragma unroll
    for (int i = 0; i < 4; i++)
#pragma unroll
        for (int j = 0; j < 4; j++)
#pragma unroll
            for (int r = 0; r < 4; r++) {
                int ri = wm + i * 16 + lg * 4 + r;
                int cj = wn + j * 16 + lm;
                int gi = it * 128 + ri;
                float v0 = acc0[i][j][r] * 0.03125f;
                if (jt0 * 128 + cj > gi) v0 = -30000.0f;
                Sp0[ri * 128 + cj] = __half_as_ushort(__float2half(v0));
                if (valid1) {
                    float v1 = acc1[i][j][r] * 0.03125f;
                    if (jt1 * 128 + cj > gi) v1 = -30000.0f;
                    Sp1[ri * 128 + cj] = __half_as_ushort(__float2half(v1));
                }
            }
}

// ---------------------------------------------------------------------------
// Row softmax over packed tiles: one wave per row, f16 -> bf16 in place + 1/l.
// Reversed order so heavy rows (large it) dispatch first.
// ---------------------------------------------------------------------------
__global__ __launch_bounds__(256) void row_softmax(u16* __restrict__ S,
                                                   float* __restrict__ inv_l) {
    int wave = threadIdx.x >> 6, lane = threadIdx.x & 63;
    int gr = 16383 - (blockIdx.x * 4 + wave);
    int b  = gr >> 12;
    int r  = gr & 4095;
    int it = r >> 7, ri = r & 127;
    u16* base = S + (long)(b * 528 + ((it * (it + 1)) >> 1)) * 16384 + ri * 128;
    int c = lane * 2;

    float m = -1e30f;
    for (int jt = 0; jt <= it; jt++) {
        u32 v = *(const u32*)&base[jt * 16384 + c];
        float a0 = __half2float(__ushort_as_half((u16)(v & 0xffff)));
        float a1 = __half2float(__ushort_as_half((u16)(v >> 16)));
        m = fmaxf(m, fmaxf(a0, a1));
    }
#pragma unroll
    for (int o = 32; o; o >>= 1) m = fmaxf(m, __shfl_xor(m, o, 64));

    const float LOG2E = 1.44269504088896f;
    float l = 0.0f;
    for (int jt = 0; jt <= it; jt++) {
        u32 v = *(const u32*)&base[jt * 16384 + c];
        float a0 = __half2float(__ushort_as_half((u16)(v & 0xffff)));
        float a1 = __half2float(__ushort_as_half((u16)(v >> 16)));
        float p0 = exp2f((a0 - m) * LOG2E);
        float p1 = exp2f((a1 - m) * LOG2E);
        u32 o = (u32)f2bf(p0) | ((u32)f2bf(p1) << 16);
        *(u32*)&base[jt * 16384 + c] = o;
        l += p0 + p1;
    }
#pragma unroll
    for (int o = 32; o; o >>= 1) l += __shfl_xor(l, o, 64);
    if (lane == 0) inv_l[gr] = 1.0f / l;
}

// ---------------------------------------------------------------------------
// O = P @ V: 128 rows x 256 cols per block, grid 512, balance-aware mapping.
// ---------------------------------------------------------------------------
__global__ __launch_bounds__(256, 2) void pv_gemm(const u16* __restrict__ P,
                                                  const u16* __restrict__ Vt,
                                                  const float* __restrict__ inv_l,
                                                  float* __restrict__ Out) {
    __shared__ u16 sA[8192], sB[16384];
    int g  = blockIdx.x;
    int it = (g < 256) ? (31 - (g >> 4)) : ((g - 256) >> 4);
    int rem = g & 15;
    int b   = rem >> 2;
    int atp = rem & 3;

    const int t  = threadIdx.x;
    const int sr = t >> 2;
    const int sc = (((t & 3) ^ ((t >> 3) & 3)) << 3);

    const u16* Pbase = P + (long)(b * 528 + ((it * (it + 1)) >> 1)) * 16384;
    const u16* gA0 = Pbase + sr * 128 + sc;
    const u16* gA1 = gA0 + 64 * 128;
    const u16* gB0 = Vt + (long)b * 4194304 + (long)(atp * 256 + sr) * 4096 + sc;
    const u16* gB1 = gB0 + (long)64 * 4096;
    const u16* gC0 = gB0 + (long)128 * 4096;
    const u16* gC1 = gB0 + (long)192 * 4096;

    f32x4 acc0[4][4] = {}, acc1[4][4] = {};
    auto addr = [&](int k, const u16*& a0, const u16*& a1, const u16*& b0,
                    const u16*& b1, const u16*& c0, const u16*& c1) {
        int jt = k >> 2, kk = (k & 3) << 5;
        long aoff = (long)jt * 16384 + kk;
        long boff = (long)jt * 128 + kk;
        a0 = gA0 + aoff; a1 = gA1 + aoff;
        b0 = gB0 + boff; b1 = gB1 + boff;
        c0 = gC0 + boff; c1 = gC1 + boff;
    };
    gemm_pipe((it + 1) * 4, addr, acc0, acc1, sA, sB);

    int lane = t & 63, wave = t >> 6;
    int wm = (wave & 1) << 6, wn = (wave >> 1) << 6, lm = lane & 15, lg = lane >> 4;
#pragma unroll
    for (int i = 0; i < 4; i++)
#pragma unroll
        for (int j = 0; j < 4; j++)
#pragma unroll
            for (int r = 0; r < 4; r++) {
                int gi = it * 128 + wm + i * 16 + lg * 4 + r;
                int ga = atp * 256 + wn + j * 16 + lm;
                float s = inv_l[b * 4096 + gi];
                Out[((long)b * 4096 + gi) * 1024 + ga]       = acc0[i][j][r] * s;
                Out[((long)b * 4096 + gi) * 1024 + ga + 128] = acc1[i][j][r] * s;
            }
}

// ---------------------------------------------------------------------------
// Workspace layout (bytes): same as R1/R2.
//   Qb   [0,          33554432)
//   Kb   [33554432,   67108864)
//   Vt   [67108864,  100663296)
//   invl [100663296, 100728832)
//   Xb   [100728832, 134283264)   (dead after proj_all)
//   Wqt/Wkt/Wvt [134283264, 140574720)  (dead after proj_all)
//   S    [100728832, 169934848)   packed tri tiles, overlays Xb+W
// ---------------------------------------------------------------------------
extern "C" void kernel_launch(void* const* d_in, const int* in_sizes, int n_in,
                              void* d_out, int out_size, void* d_ws, size_t ws_size,
                              hipStream_t stream) {
    const float* X  = (const float*)d_in[0];
    const float* Wk = (const float*)d_in[1];
    const float* Wq = (const float*)d_in[2];
    const float* Wv = (const float*)d_in[3];
    float* Out = (float*)d_out;

    char* w = (char*)d_ws;
    u16*   Qb   = (u16*)(w);
    u16*   Kb   = (u16*)(w + 33554432);
    u16*   Vt   = (u16*)(w + 67108864);
    float* invl = (float*)(w + 100663296);
    u16*   Xb   = (u16*)(w + 100728832);
    u16*   Wqt  = (u16*)(w + 134283264);
    u16*   Wkt  = (u16*)(w + 136380416);
    u16*   Wvt  = (u16*)(w + 138477568);
    u16*   S    = (u16*)(w + 100728832);

    convert_x<<<16384, 256, 0, stream>>>(X, Xb);
    convert_w<<<dim3(256, 3), 256, 0, stream>>>(Wk, Wq, Wv, Wkt, Wqt, Wvt);
    proj_all<<<1536, 256, 0, stream>>>(Xb, Wqt, Wkt, Wvt, Qb, Kb, Vt);
    sgemm_causal<<<1088, 256, 0, stream>>>(Qb, Kb, S);
    row_softmax<<<4096, 256, 0, stream>>>(S, invl);
    pv_gemm<<<512, 256, 0, stream>>>(S, Vt, invl, Out);
}